// Round 3
// baseline (9.680 us; speedup 1.0000x reference)
//
#include <hip/hip_runtime.h>

// AE loss: tags [B,N,1] f32, joints [B,P,J,2] i32 (flat_idx, vis)
// outputs: push [B], pull [B]  -> d_out = [push(32) | pull(32)] f32
#define AE_B 32
#define AE_N (17 * 256 * 256)
#define AE_P 30
#define AE_J 17
#define AE_JI (AE_P * AE_J * 2)   // 1020 ints per batch, = 255 * int4 exactly

__global__ __launch_bounds__(64) void ae_loss_kernel(
    const float* __restrict__ tags,
    const int*   __restrict__ joints,
    float*       __restrict__ out)
{
    const int b = blockIdx.x;
    const int t = threadIdx.x;

    __shared__ int   s_j[AE_JI];   // staged joints for this batch
    __shared__ float s_mean[AE_P]; // valid: mean tag; invalid: huge sentinel

    const float* tb = tags + (size_t)b * AE_N;

    // coalesced stage of this batch's joints: 255 int4 loads across the wave
    {
        const int4* jb4 = reinterpret_cast<const int4*>(joints + (size_t)b * AE_JI);
        #pragma unroll
        for (int i = 0; i < 4; ++i) {
            int slot = i * 64 + t;
            if (slot < AE_JI / 4) {
                int4 v = jb4[slot];
                s_j[slot * 4 + 0] = v.x;
                s_j[slot * 4 + 1] = v.y;
                s_j[slot * 4 + 2] = v.z;
                s_j[slot * 4 + 3] = v.w;
            }
        }
    }
    __syncthreads();

    float pullv  = 0.f;   // pull_p * valid_p   (lane t = person t)
    float validf = 0.f;   // valid_p
    if (t < AE_P) {
        const int* jp = s_j + t * AE_J * 2;
        float g[AE_J], v[AE_J];
        float cnt = 0.f, sum = 0.f;
        #pragma unroll
        for (int j = 0; j < AE_J; ++j) {
            int idx = jp[2 * j + 0];
            int vis = jp[2 * j + 1];
            float vf = (vis > 0) ? 1.f : 0.f;
            float gv = tb[idx];          // independent gathers, one vmcnt wait
            g[j] = gv;
            v[j] = vf;
            cnt += vf;
            sum += gv * vf;
        }
        const float safe = fmaxf(cnt, 1.f);
        const float mean = sum / safe;
        float pull = 0.f;
        #pragma unroll
        for (int j = 0; j < AE_J; ++j) {
            float d = g[j] - mean;
            pull += d * d * v[j];
        }
        validf = (cnt > 0.f) ? 1.f : 0.f;
        pullv  = (pull / safe) * validf;
        // sentinel trick: invalid people get distinct huge means so every
        // pair involving one goes exp(-inf)=0, except its own diagonal (=1).
        // Then masked_sum - num == psum - P exactly.
        s_mean[t] = (cnt > 0.f) ? mean : 1e18f * (float)(t + 1);
    }
    __syncthreads();

    // all 64 lanes split the P*P = 900 push pairs (no mask needed)
    float psum = 0.f;
    for (int pair = t; pair < AE_P * AE_P; pair += 64) {
        int p = pair / AE_P;
        int q = pair - p * AE_P;
        float d = s_mean[p] - s_mean[q];
        psum += __expf(-d * d);
    }

    // wave-64 butterfly reduce: psum, pullv, validf together
    #pragma unroll
    for (int off = 32; off > 0; off >>= 1) {
        psum   += __shfl_down(psum, off);
        pullv  += __shfl_down(pullv, off);
        validf += __shfl_down(validf, off);
    }

    if (t == 0) {
        const float num      = validf;
        const float pull     = pullv / fmaxf(num, 1.f);
        const float push_sum = psum - (float)AE_P;   // == masked_sum - num
        const float denom    = fmaxf((num - 1.f) * num, 1.f);
        const float push     = (num > 1.f) ? push_sum / denom * 0.5f : 0.f;
        out[b]        = push;   // output 0: push
        out[AE_B + b] = pull;   // output 1: pull
    }
}

extern "C" void kernel_launch(void* const* d_in, const int* in_sizes, int n_in,
                              void* d_out, int out_size, void* d_ws, size_t ws_size,
                              hipStream_t stream) {
    const float* tags   = (const float*)d_in[0];
    const int*   joints = (const int*)d_in[1];
    float*       out    = (float*)d_out;
    ae_loss_kernel<<<AE_B, 64, 0, stream>>>(tags, joints, out);
}